// Round 2
// baseline (810.908 us; speedup 1.0000x reference)
//
#include <hip/hip_runtime.h>
#include <math.h>

// ===========================================================================
// EnergyGCN: h = relu(x@W1+b1); h0=h;
//   L times: t = h@Wr[l]^T; s = Ahat@t; v = g_l*h0 + 6t - 3s; h0=v; h=relu(v)
//   out = h@W2 + b2
// Ahat = D^-1/2 (A+I) D^-1/2 built from edge_index (row->col gather, scatter to row)
// Strategy: device-side CSR build (count/scan/fill), gather-style SpMM fused
// with the residual update, LDS-tiled fp32 GEMMs.
// ===========================================================================

#define GBLK 256

// ---------------- CSR build ----------------
__global__ void k_count(const int* __restrict__ eidx, int* __restrict__ degi, int E, int n) {
  int e = blockIdx.x * blockDim.x + threadIdx.x;
  if (e < E) {
    int r = eidx[e];
    if ((unsigned)r < (unsigned)n) atomicAdd(&degi[r], 1);
  }
}

__global__ __launch_bounds__(1024) void k_scan1(const int* __restrict__ degi,
                                                int* __restrict__ rowstart,
                                                int* __restrict__ bsum, int n) {
  __shared__ int sm[1024];
  int tid = threadIdx.x;
  int i = blockIdx.x * 1024 + tid;
  int v = (i < n) ? degi[i] : 0;
  sm[tid] = v;
  __syncthreads();
  #pragma unroll
  for (int off = 1; off < 1024; off <<= 1) {
    int t = (tid >= off) ? sm[tid - off] : 0;
    __syncthreads();
    sm[tid] += t;
    __syncthreads();
  }
  if (i < n) rowstart[i] = sm[tid] - v;  // exclusive within block
  if (tid == 1023) bsum[blockIdx.x] = sm[1023];
}

__global__ void k_scan2(const int* __restrict__ bsum, int* __restrict__ boff, int nb) {
  if (threadIdx.x == 0 && blockIdx.x == 0) {
    int s = 0;
    for (int b = 0; b < nb; ++b) { boff[b] = s; s += bsum[b]; }
  }
}

__global__ __launch_bounds__(1024) void k_scan3(int* __restrict__ rowstart,
                                                const int* __restrict__ boff,
                                                int* __restrict__ cursor, int n, int E) {
  int i = blockIdx.x * 1024 + threadIdx.x;
  if (i < n) {
    int v = rowstart[i] + boff[blockIdx.x];
    rowstart[i] = v;
    cursor[i] = v;
  }
  if (i == 0) rowstart[n] = E;
}

__global__ void k_dinv(const int* __restrict__ degi, float* __restrict__ dinv, int n) {
  int i = blockIdx.x * blockDim.x + threadIdx.x;
  if (i < n) dinv[i] = rsqrtf((float)degi[i] + 1.0f);  // +1 = self loop
}

__global__ void k_fill(const int* __restrict__ eidx, int* __restrict__ cursor,
                       int* __restrict__ colidx, int E, int n) {
  int e = blockIdx.x * blockDim.x + threadIdx.x;
  if (e < E) {
    int r = eidx[e];
    int c = eidx[E + e];
    if ((unsigned)r < (unsigned)n && (unsigned)c < (unsigned)n) {
      int pos = atomicAdd(&cursor[r], 1);
      colidx[pos] = c;
    }
  }
}

// ---------------- GEMM: C[n,NOUT] = act(A[n,K] @ B (+bias)) ----------------
// Block: 256 threads, 64-row group. Each thread: RT rows x 4 cols register tile.
// KT=64 K-tiles staged in LDS (W padded +4 to keep float4 alignment + spread banks).
template <int K, int NOUT, bool TRANSB, bool BIAS, bool RELU, bool DUP>
__global__ __launch_bounds__(GBLK) void gemm_kernel(const float* __restrict__ A,
                                                    const float* __restrict__ B,
                                                    const float* __restrict__ bias,
                                                    float* __restrict__ C,
                                                    float* __restrict__ C2, int n) {
  constexpr int KT = 64;
  constexpr int CT = 4;
  constexpr int NCT = NOUT / CT;   // col-thread count (32 / 16)
  constexpr int RS = GBLK / NCT;   // row subgroups (8 / 16)
  constexpr int RT = 64 / RS;      // rows per thread (8 / 4)
  constexpr int ROWS = 64;
  constexpr int WP = NOUT + 4;     // padded LDS stride (keeps 16B align)

  __shared__ __align__(16) float Wl[KT][WP];
  __shared__ __align__(16) float Hl[ROWS][KT];

  const int tid = threadIdx.x;
  const int row0 = blockIdx.x * ROWS;
  const int jc = (tid % NCT) * CT;
  const int r0 = (tid / NCT) * RT;

  float acc[RT][CT];
  #pragma unroll
  for (int r = 0; r < RT; ++r)
    #pragma unroll
    for (int c = 0; c < CT; ++c) acc[r][c] = 0.0f;

  for (int kt = 0; kt < K; kt += KT) {
    // stage W tile: Wl[k][j]
    if (TRANSB) {  // B is [NOUT][K]
      for (int m = tid; m < KT * NOUT; m += GBLK) {
        int j = m / KT, k = m % KT;
        Wl[k][j] = B[j * K + kt + k];
      }
    } else {       // B is [K][NOUT]
      for (int m = tid; m < KT * NOUT; m += GBLK) {
        int k = m / NOUT, j = m % NOUT;
        Wl[k][j] = B[(kt + k) * NOUT + j];
      }
    }
    // stage A tile rows (float4)
    constexpr int KT4 = KT / 4;
    for (int m = tid; m < ROWS * KT4; m += GBLK) {
      int r = m / KT4, kq = m % KT4;
      int row = row0 + r;
      float4 v = make_float4(0.f, 0.f, 0.f, 0.f);
      if (row < n) v = *(const float4*)&A[(size_t)row * K + kt + kq * 4];
      *(float4*)&Hl[r][kq * 4] = v;
    }
    __syncthreads();

    #pragma unroll
    for (int k = 0; k < KT; ++k) {
      float4 wv = *(const float4*)&Wl[k][jc];
      #pragma unroll
      for (int r = 0; r < RT; ++r) {
        float hv = Hl[r0 + r][k];
        acc[r][0] += hv * wv.x;
        acc[r][1] += hv * wv.y;
        acc[r][2] += hv * wv.z;
        acc[r][3] += hv * wv.w;
      }
    }
    __syncthreads();
  }

  float4 bv = make_float4(0.f, 0.f, 0.f, 0.f);
  if (BIAS) bv = *(const float4*)&bias[jc];
  #pragma unroll
  for (int r = 0; r < RT; ++r) {
    int row = row0 + r0 + r;
    if (row < n) {
      float4 v;
      v.x = acc[r][0] + bv.x;
      v.y = acc[r][1] + bv.y;
      v.z = acc[r][2] + bv.z;
      v.w = acc[r][3] + bv.w;
      if (RELU) {
        v.x = fmaxf(v.x, 0.f); v.y = fmaxf(v.y, 0.f);
        v.z = fmaxf(v.z, 0.f); v.w = fmaxf(v.w, 0.f);
      }
      *(float4*)&C[(size_t)row * NOUT + jc] = v;
      if (DUP) *(float4*)&C2[(size_t)row * NOUT + jc] = v;
    }
  }
}

// ---------------- fused SpMM (gather) + residual update ----------------
// s[r] = dinv[r] * ( sum_{e in row r} dinv[c_e]*t[c_e] + dinv[r]*t[r] )
// v = g*h0 + 6t - 3s; h0 = v; h = relu(v)
__global__ __launch_bounds__(128) void k_spmm(const float* __restrict__ t,
                                              const float* __restrict__ dinv,
                                              const int* __restrict__ rowstart,
                                              const int* __restrict__ colidx,
                                              const float* __restrict__ eps, int layer,
                                              float* __restrict__ h0,
                                              float* __restrict__ h, int n) {
  int r = blockIdx.x;
  if (r >= n) return;
  int j = threadIdx.x;
  int s0 = rowstart[r], s1 = rowstart[r + 1];
  float dr = dinv[r];
  size_t idx = (size_t)r * 128 + j;
  float tv = t[idx];
  float acc = dr * tv;  // self loop term (inner)
  for (int e = s0; e < s1; ++e) {
    int c = colidx[e];
    acc += dinv[c] * t[(size_t)c * 128 + j];
  }
  float s = dr * acc;
  float g = 1.0f + tanhf(eps[layer]);
  float v = g * h0[idx] + 6.0f * tv - 3.0f * s;
  h0[idx] = v;
  h[idx] = fmaxf(v, 0.0f);
}

// ---------------- launch ----------------
extern "C" void kernel_launch(void* const* d_in, const int* in_sizes, int n_in,
                              void* d_out, int out_size, void* d_ws, size_t ws_size,
                              hipStream_t stream) {
  const float* x   = (const float*)d_in[0];
  const float* W1  = (const float*)d_in[1];
  const float* b1  = (const float*)d_in[2];
  const float* Wr  = (const float*)d_in[3];
  const float* eps = (const float*)d_in[4];
  const float* W2  = (const float*)d_in[5];
  const float* b2  = (const float*)d_in[6];
  const int*   eidx= (const int*)d_in[7];

  const int IN = 256, H = 128;
  const int n = in_sizes[0] / IN;   // 50000
  const int E = in_sizes[7] / 2;    // 800000
  const int L = in_sizes[4];        // 4

  // workspace carve (256B aligned)
  size_t off = 0;
  auto carve = [&](size_t bytes) -> void* {
    void* p = (char*)d_ws + off;
    off += (bytes + 255) & ~(size_t)255;
    return p;
  };
  int*   degi     = (int*)carve((size_t)n * 4);
  int*   rowstart = (int*)carve((size_t)(n + 1) * 4);
  int*   cursor   = (int*)carve((size_t)n * 4);
  int*   bsum     = (int*)carve(64 * 4);
  int*   boff     = (int*)carve(64 * 4);
  int*   colidx   = (int*)carve((size_t)E * 4);
  float* dinv     = (float*)carve((size_t)n * 4);
  float* h        = (float*)carve((size_t)n * H * 4);
  float* h0       = (float*)carve((size_t)n * H * 4);
  float* t        = (float*)carve((size_t)n * H * 4);
  if (off > ws_size) return;  // insufficient workspace: fail loudly (zeros out)

  // ---- CSR build ----
  hipMemsetAsync(degi, 0, (size_t)n * 4, stream);
  k_count<<<(E + 255) / 256, 256, 0, stream>>>(eidx, degi, E, n);
  int nb = (n + 1023) / 1024;
  k_scan1<<<nb, 1024, 0, stream>>>(degi, rowstart, bsum, n);
  k_scan2<<<1, 64, 0, stream>>>(bsum, boff, nb);
  k_scan3<<<nb, 1024, 0, stream>>>(rowstart, boff, cursor, n, E);
  k_dinv<<<(n + 255) / 256, 256, 0, stream>>>(degi, dinv, n);
  k_fill<<<(E + 255) / 256, 256, 0, stream>>>(eidx, cursor, colidx, E, n);

  int gx = (n + 63) / 64;
  // ---- lin1 + relu -> h, h0 ----
  gemm_kernel<256, 128, false, true, true, true><<<gx, GBLK, 0, stream>>>(x, W1, b1, h, h0, n);
  // ---- layers ----
  for (int l = 0; l < L; ++l) {
    gemm_kernel<128, 128, true, false, false, false><<<gx, GBLK, 0, stream>>>(
        h, Wr + (size_t)l * H * H, nullptr, t, nullptr, n);
    k_spmm<<<n, 128, 0, stream>>>(t, dinv, rowstart, colidx, eps, l, h0, h, n);
  }
  // ---- lin2 -> out ----
  gemm_kernel<128, 64, false, true, false, false><<<gx, GBLK, 0, stream>>>(
      h, W2, b2, (float*)d_out, nullptr, n);
}

// Round 6
// 604.601 us; speedup vs baseline: 1.3412x; 1.3412x over previous
//
#include <hip/hip_runtime.h>
#include <math.h>

// ===========================================================================
// EnergyGCN: h = relu(x@W1+b1); h0=h;
//   L times: t = h@Wr[l]^T; s = Ahat@t; v = g_l*h0 + 6t - 3s; h0=v; h=relu(v)
//   out = h@W2 + b2
// Round 3: SpMM gathers from a bf16 dinv-scaled copy `pre` (written by the
// lin_right GEMM epilogue) -> half gather bytes, no per-edge multiply.
// Wave-per-row with shfl-broadcast indices kills the dependent-load chain.
// ===========================================================================

#define GBLK 256

__device__ __forceinline__ ushort f2bf(float f) {  // RNE float->bf16
  unsigned u = __float_as_uint(f);
  return (ushort)((u + 0x7fffu + ((u >> 16) & 1u)) >> 16);
}

// ---------------- CSR build ----------------
__global__ void k_count(const int* __restrict__ eidx, int* __restrict__ degi, int E, int n) {
  int e = blockIdx.x * blockDim.x + threadIdx.x;
  if (e < E) {
    int r = eidx[e];
    if ((unsigned)r < (unsigned)n) atomicAdd(&degi[r], 1);
  }
}

__global__ __launch_bounds__(1024) void k_scan1(const int* __restrict__ degi,
                                                int* __restrict__ rowstart,
                                                int* __restrict__ bsum, int n) {
  __shared__ int sm[1024];
  int tid = threadIdx.x;
  int i = blockIdx.x * 1024 + tid;
  int v = (i < n) ? degi[i] : 0;
  sm[tid] = v;
  __syncthreads();
  #pragma unroll
  for (int off = 1; off < 1024; off <<= 1) {
    int t = (tid >= off) ? sm[tid - off] : 0;
    __syncthreads();
    sm[tid] += t;
    __syncthreads();
  }
  if (i < n) rowstart[i] = sm[tid] - v;  // exclusive within block
  if (tid == 1023) bsum[blockIdx.x] = sm[1023];
}

__global__ void k_scan2(const int* __restrict__ bsum, int* __restrict__ boff, int nb) {
  if (threadIdx.x == 0 && blockIdx.x == 0) {
    int s = 0;
    for (int b = 0; b < nb; ++b) { boff[b] = s; s += bsum[b]; }
  }
}

__global__ __launch_bounds__(1024) void k_scan3(int* __restrict__ rowstart,
                                                const int* __restrict__ boff,
                                                int* __restrict__ cursor, int n, int E) {
  int i = blockIdx.x * 1024 + threadIdx.x;
  if (i < n) {
    int v = rowstart[i] + boff[blockIdx.x];
    rowstart[i] = v;
    cursor[i] = v;
  }
  if (i == 0) rowstart[n] = E;
}

__global__ void k_dinv(const int* __restrict__ degi, float* __restrict__ dinv, int n) {
  int i = blockIdx.x * blockDim.x + threadIdx.x;
  if (i < n) dinv[i] = rsqrtf((float)degi[i] + 1.0f);  // +1 = self loop
}

__global__ void k_fill(const int* __restrict__ eidx, int* __restrict__ cursor,
                       int* __restrict__ colidx, int E, int n) {
  int e = blockIdx.x * blockDim.x + threadIdx.x;
  if (e < E) {
    int r = eidx[e];
    int c = eidx[E + e];
    if ((unsigned)r < (unsigned)n && (unsigned)c < (unsigned)n) {
      int pos = atomicAdd(&cursor[r], 1);
      colidx[pos] = c;
    }
  }
}

// ---------------- GEMM: C[n,NOUT] = act(A[n,K] @ B (+bias)) ----------------
// BF16S: write ushort C as bf16 of (acc * scale[row]) -- for lin_right -> pre.
template <int K, int NOUT, bool TRANSB, bool BIAS, bool RELU, bool DUP, bool BF16S>
__global__ __launch_bounds__(GBLK) void gemm_kernel(const float* __restrict__ A,
                                                    const float* __restrict__ B,
                                                    const float* __restrict__ bias,
                                                    float* __restrict__ C,
                                                    float* __restrict__ C2,
                                                    const float* __restrict__ scale,
                                                    int n) {
  constexpr int KT = 64;
  constexpr int CT = 4;
  constexpr int NCT = NOUT / CT;   // col-thread count (32 / 16)
  constexpr int RS = GBLK / NCT;   // row subgroups (8 / 16)
  constexpr int RT = 64 / RS;      // rows per thread (8 / 4)
  constexpr int ROWS = 64;
  constexpr int WP = NOUT + 4;     // padded LDS stride (keeps 16B align)

  __shared__ __align__(16) float Wl[KT][WP];
  __shared__ __align__(16) float Hl[ROWS][KT];

  const int tid = threadIdx.x;
  const int row0 = blockIdx.x * ROWS;
  const int jc = (tid % NCT) * CT;
  const int r0 = (tid / NCT) * RT;

  float acc[RT][CT];
  #pragma unroll
  for (int r = 0; r < RT; ++r)
    #pragma unroll
    for (int c = 0; c < CT; ++c) acc[r][c] = 0.0f;

  for (int kt = 0; kt < K; kt += KT) {
    if (TRANSB) {  // B is [NOUT][K]
      for (int m = tid; m < KT * NOUT; m += GBLK) {
        int j = m / KT, k = m % KT;
        Wl[k][j] = B[j * K + kt + k];
      }
    } else {       // B is [K][NOUT]
      for (int m = tid; m < KT * NOUT; m += GBLK) {
        int k = m / NOUT, j = m % NOUT;
        Wl[k][j] = B[(kt + k) * NOUT + j];
      }
    }
    constexpr int KT4 = KT / 4;
    for (int m = tid; m < ROWS * KT4; m += GBLK) {
      int r = m / KT4, kq = m % KT4;
      int row = row0 + r;
      float4 v = make_float4(0.f, 0.f, 0.f, 0.f);
      if (row < n) v = *(const float4*)&A[(size_t)row * K + kt + kq * 4];
      *(float4*)&Hl[r][kq * 4] = v;
    }
    __syncthreads();

    #pragma unroll
    for (int k = 0; k < KT; ++k) {
      float4 wv = *(const float4*)&Wl[k][jc];
      #pragma unroll
      for (int r = 0; r < RT; ++r) {
        float hv = Hl[r0 + r][k];
        acc[r][0] += hv * wv.x;
        acc[r][1] += hv * wv.y;
        acc[r][2] += hv * wv.z;
        acc[r][3] += hv * wv.w;
      }
    }
    __syncthreads();
  }

  if constexpr (BF16S) {
    #pragma unroll
    for (int r = 0; r < RT; ++r) {
      int row = row0 + r0 + r;
      if (row < n) {
        float sc = scale[row];
        ushort4 o;
        o.x = f2bf(acc[r][0] * sc);
        o.y = f2bf(acc[r][1] * sc);
        o.z = f2bf(acc[r][2] * sc);
        o.w = f2bf(acc[r][3] * sc);
        *(ushort4*)&(((ushort*)C)[(size_t)row * NOUT + jc]) = o;
      }
    }
  } else {
    float4 bv = make_float4(0.f, 0.f, 0.f, 0.f);
    if (BIAS) bv = *(const float4*)&bias[jc];
    #pragma unroll
    for (int r = 0; r < RT; ++r) {
      int row = row0 + r0 + r;
      if (row < n) {
        float4 v;
        v.x = acc[r][0] + bv.x;
        v.y = acc[r][1] + bv.y;
        v.z = acc[r][2] + bv.z;
        v.w = acc[r][3] + bv.w;
        if (RELU) {
          v.x = fmaxf(v.x, 0.f); v.y = fmaxf(v.y, 0.f);
          v.z = fmaxf(v.z, 0.f); v.w = fmaxf(v.w, 0.f);
        }
        *(float4*)&C[(size_t)row * NOUT + jc] = v;
        if (DUP) *(float4*)&C2[(size_t)row * NOUT + jc] = v;
      }
    }
  }
}

// ---------------- fused SpMM (bf16 gather) + residual update ----------------
// pre[c] = bf16(dinv[c] * t[c])  (written by lin_right epilogue)
// v = g*h0 + ((6-3*dr^2)/dr)*pre[r] - 3*dr*sum_nb(pre[c]);  h0=v; h=relu(v)
// One wave per row (lane owns 2 cols = one 4B bf16x2 load per edge);
// edge indices loaded coalesced once per 64-chunk, broadcast via shfl.
__global__ __launch_bounds__(256) void k_spmm2(const ushort* __restrict__ pre,
                                               const float* __restrict__ dinv,
                                               const int* __restrict__ rowstart,
                                               const int* __restrict__ colidx,
                                               const float* __restrict__ eps, int layer,
                                               float* __restrict__ h0,
                                               float* __restrict__ h, int n) {
  const int lane = threadIdx.x & 63;
  const int r = blockIdx.x * 4 + (threadIdx.x >> 6);
  if (r >= n) return;

  const int s0 = rowstart[r], s1 = rowstart[r + 1];
  const float dr = dinv[r];

  // issue own-row + h0 loads early (overlap with gather loop)
  const size_t rowoff = (size_t)r * 128 + lane * 2;
  const unsigned ur = *(const unsigned*)&pre[rowoff];
  const float2 h0v = *(const float2*)&h0[rowoff];

  float accx = 0.f, accy = 0.f;
  for (int base = s0; base < s1; base += 64) {
    int m = s1 - base; if (m > 64) m = 64;
    int ci = 0;
    if (base + lane < s1) ci = colidx[base + lane];
    int e = 0;
    for (; e + 3 < m; e += 4) {
      int c0 = __shfl(ci, e);
      int c1 = __shfl(ci, e + 1);
      int c2 = __shfl(ci, e + 2);
      int c3 = __shfl(ci, e + 3);
      unsigned u0 = *(const unsigned*)&pre[(size_t)c0 * 128 + lane * 2];
      unsigned u1 = *(const unsigned*)&pre[(size_t)c1 * 128 + lane * 2];
      unsigned u2 = *(const unsigned*)&pre[(size_t)c2 * 128 + lane * 2];
      unsigned u3 = *(const unsigned*)&pre[(size_t)c3 * 128 + lane * 2];
      accx += __uint_as_float(u0 << 16);
      accy += __uint_as_float(u0 & 0xffff0000u);
      accx += __uint_as_float(u1 << 16);
      accy += __uint_as_float(u1 & 0xffff0000u);
      accx += __uint_as_float(u2 << 16);
      accy += __uint_as_float(u2 & 0xffff0000u);
      accx += __uint_as_float(u3 << 16);
      accy += __uint_as_float(u3 & 0xffff0000u);
    }
    for (; e < m; ++e) {
      int c = __shfl(ci, e);
      unsigned u = *(const unsigned*)&pre[(size_t)c * 128 + lane * 2];
      accx += __uint_as_float(u << 16);
      accy += __uint_as_float(u & 0xffff0000u);
    }
  }

  const float p0 = __uint_as_float(ur << 16);
  const float p1 = __uint_as_float(ur & 0xffff0000u);
  const float a = (6.0f - 3.0f * dr * dr) / dr;
  const float m3dr = -3.0f * dr;
  const float g = 1.0f + tanhf(eps[layer]);

  float v0 = g * h0v.x + a * p0 + m3dr * accx;
  float v1 = g * h0v.y + a * p1 + m3dr * accy;
  *(float2*)&h0[rowoff] = make_float2(v0, v1);
  *(float2*)&h[rowoff] = make_float2(fmaxf(v0, 0.f), fmaxf(v1, 0.f));
}

// ---------------- launch ----------------
extern "C" void kernel_launch(void* const* d_in, const int* in_sizes, int n_in,
                              void* d_out, int out_size, void* d_ws, size_t ws_size,
                              hipStream_t stream) {
  const float* x   = (const float*)d_in[0];
  const float* W1  = (const float*)d_in[1];
  const float* b1  = (const float*)d_in[2];
  const float* Wr  = (const float*)d_in[3];
  const float* eps = (const float*)d_in[4];
  const float* W2  = (const float*)d_in[5];
  const float* b2  = (const float*)d_in[6];
  const int*   eidx= (const int*)d_in[7];

  const int IN = 256, H = 128;
  const int n = in_sizes[0] / IN;   // 50000
  const int E = in_sizes[7] / 2;    // 800000
  const int L = in_sizes[4];        // 4

  size_t off = 0;
  auto carve = [&](size_t bytes) -> void* {
    void* p = (char*)d_ws + off;
    off += (bytes + 255) & ~(size_t)255;
    return p;
  };
  int*    degi     = (int*)carve((size_t)n * 4);
  int*    rowstart = (int*)carve((size_t)(n + 1) * 4);
  int*    cursor   = (int*)carve((size_t)n * 4);
  int*    bsum     = (int*)carve(64 * 4);
  int*    boff     = (int*)carve(64 * 4);
  int*    colidx   = (int*)carve((size_t)E * 4);
  float*  dinv     = (float*)carve((size_t)n * 4);
  float*  h        = (float*)carve((size_t)n * H * 4);
  float*  h0       = (float*)carve((size_t)n * H * 4);
  ushort* pre      = (ushort*)carve((size_t)n * H * 2);
  if (off > ws_size) return;

  // ---- CSR build ----
  hipMemsetAsync(degi, 0, (size_t)n * 4, stream);
  k_count<<<(E + 255) / 256, 256, 0, stream>>>(eidx, degi, E, n);
  int nb = (n + 1023) / 1024;
  k_scan1<<<nb, 1024, 0, stream>>>(degi, rowstart, bsum, n);
  k_scan2<<<1, 64, 0, stream>>>(bsum, boff, nb);
  k_scan3<<<nb, 1024, 0, stream>>>(rowstart, boff, cursor, n, E);
  k_dinv<<<(n + 255) / 256, 256, 0, stream>>>(degi, dinv, n);
  k_fill<<<(E + 255) / 256, 256, 0, stream>>>(eidx, cursor, colidx, E, n);

  int gx = (n + 63) / 64;
  // ---- lin1 + relu -> h, h0 (fp32) ----
  gemm_kernel<256, 128, false, true, true, true, false><<<gx, GBLK, 0, stream>>>(
      x, W1, b1, h, h0, nullptr, n);
  // ---- layers ----
  for (int l = 0; l < L; ++l) {
    // t = h@Wr^T, scaled by dinv[row], emitted as bf16 `pre`
    gemm_kernel<128, 128, true, false, false, false, true><<<gx, GBLK, 0, stream>>>(
        h, Wr + (size_t)l * H * H, nullptr, (float*)pre, nullptr, dinv, n);
    k_spmm2<<<(n + 3) / 4, 256, 0, stream>>>(pre, dinv, rowstart, colidx, eps, l, h0, h, n);
  }
  // ---- lin2 -> out ----
  gemm_kernel<128, 64, false, true, false, false, false><<<gx, GBLK, 0, stream>>>(
      h, W2, b2, (float*)d_out, nullptr, nullptr, n);
}

// Round 9
// 494.550 us; speedup vs baseline: 1.6397x; 1.2225x over previous
//
#include <hip/hip_runtime.h>
#include <math.h>

// ===========================================================================
// EnergyGCN round 7: all GEMMs -> bf16 MFMA (16x16x32), no-LDS fragment loads.
// h becomes bf16-only (h_bf); h0 stays fp32. Weights converted/transposed to
// [j][k] bf16 once per launch. SpMM unchanged from round 3 (bf16 pre gather).
// ===========================================================================

#define GBLK 256

typedef __bf16 bf16x8 __attribute__((ext_vector_type(8)));
typedef float f32x4 __attribute__((ext_vector_type(4)));
typedef unsigned int uint32x4 __attribute__((ext_vector_type(4)));

__device__ __forceinline__ ushort f2bf(float f) {  // RNE float->bf16
  unsigned u = __float_as_uint(f);
  return (ushort)((u + 0x7fffu + ((u >> 16) & 1u)) >> 16);
}

// ---------------- CSR build ----------------
__global__ void k_count(const int* __restrict__ eidx, int* __restrict__ degi, int E, int n) {
  int e = blockIdx.x * blockDim.x + threadIdx.x;
  if (e < E) {
    int r = eidx[e];
    if ((unsigned)r < (unsigned)n) atomicAdd(&degi[r], 1);
  }
}

__global__ __launch_bounds__(1024) void k_scan1(const int* __restrict__ degi,
                                                int* __restrict__ rowstart,
                                                int* __restrict__ bsum, int n) {
  __shared__ int sm[1024];
  int tid = threadIdx.x;
  int i = blockIdx.x * 1024 + tid;
  int v = (i < n) ? degi[i] : 0;
  sm[tid] = v;
  __syncthreads();
  #pragma unroll
  for (int off = 1; off < 1024; off <<= 1) {
    int t = (tid >= off) ? sm[tid - off] : 0;
    __syncthreads();
    sm[tid] += t;
    __syncthreads();
  }
  if (i < n) rowstart[i] = sm[tid] - v;
  if (tid == 1023) bsum[blockIdx.x] = sm[1023];
}

__global__ void k_scan2(const int* __restrict__ bsum, int* __restrict__ boff, int nb) {
  if (threadIdx.x == 0 && blockIdx.x == 0) {
    int s = 0;
    for (int b = 0; b < nb; ++b) { boff[b] = s; s += bsum[b]; }
  }
}

__global__ __launch_bounds__(1024) void k_scan3(int* __restrict__ rowstart,
                                                const int* __restrict__ boff,
                                                int* __restrict__ cursor, int n, int E) {
  int i = blockIdx.x * 1024 + threadIdx.x;
  if (i < n) {
    int v = rowstart[i] + boff[blockIdx.x];
    rowstart[i] = v;
    cursor[i] = v;
  }
  if (i == 0) rowstart[n] = E;
}

__global__ void k_dinv(const int* __restrict__ degi, float* __restrict__ dinv, int n) {
  int i = blockIdx.x * blockDim.x + threadIdx.x;
  if (i < n) dinv[i] = rsqrtf((float)degi[i] + 1.0f);
}

__global__ void k_fill(const int* __restrict__ eidx, int* __restrict__ cursor,
                       int* __restrict__ colidx, int E, int n) {
  int e = blockIdx.x * blockDim.x + threadIdx.x;
  if (e < E) {
    int r = eidx[e];
    int c = eidx[E + e];
    if ((unsigned)r < (unsigned)n && (unsigned)c < (unsigned)n) {
      int pos = atomicAdd(&cursor[r], 1);
      colidx[pos] = c;
    }
  }
}

// ---------------- weight convert/transpose to bf16 [j][k] ----------------
// wr_bf[l][j][k] = Wr[l][j][k]; w1t[j][k] = W1[k][j]; w2t[j][k] = W2[k][j]
__global__ void k_cvt(const float* __restrict__ Wr, const float* __restrict__ W1,
                      const float* __restrict__ W2, ushort* __restrict__ wr_bf,
                      ushort* __restrict__ w1t, ushort* __restrict__ w2t,
                      int nwr, int nw1, int nw2) {
  int i = blockIdx.x * blockDim.x + threadIdx.x;
  if (i < nwr) {
    wr_bf[i] = f2bf(Wr[i]);
  } else if (i < nwr + nw1) {
    int m = i - nwr;             // m = k*128 + j  (W1 is [256][128])
    int k = m >> 7, j = m & 127;
    w1t[j * 256 + k] = f2bf(W1[m]);
  } else if (i < nwr + nw1 + nw2) {
    int m = i - nwr - nw1;       // m = k*64 + j   (W2 is [128][64])
    int k = m >> 6, j = m & 63;
    w2t[j * 128 + k] = f2bf(W2[m]);
  }
}

// ---------------- MFMA GEMM: C[n,NOUT] = A[n,K] @ Bt^T ----------------
// Bt is bf16 [NOUT][K] (j-major). 4 waves/block, 16 rows/wave, no LDS.
// A-frag: row = lane&15, k = (lane>>4)*8 + i (same assumed k-map for B ->
// any hw k-permutation cancels). C/D: col = lane&15, row = (lane>>4)*4+reg.
// EPI 0: +bias, relu -> out_bf (h_bf) + out_f32 (h0)
// EPI 1: *dinv[row]  -> out_bf (pre)
// EPI 2: +bias       -> out_f32 (d_out)
template <int K, int NOUT, bool AF32, int EPI>
__global__ __launch_bounds__(256) void mfma_gemm(const void* __restrict__ Ap,
                                                 const ushort* __restrict__ Bt,
                                                 const float* __restrict__ bias,
                                                 const float* __restrict__ dinv,
                                                 ushort* __restrict__ out_bf,
                                                 float* __restrict__ out_f32,
                                                 int n) {
  constexpr int KS = K / 32;
  constexpr int NT = NOUT / 16;
  const int lane = threadIdx.x & 63;
  const int wave = threadIdx.x >> 6;
  const int l15 = lane & 15;
  const int kq = lane >> 4;
  const int rowA = blockIdx.x * 64 + wave * 16 + l15;
  const bool arow_ok = rowA < n;

  f32x4 acc[NT];
  #pragma unroll
  for (int t = 0; t < NT; ++t) acc[t] = (f32x4){0.f, 0.f, 0.f, 0.f};

  #pragma unroll
  for (int kk = 0; kk < KS; ++kk) {
    bf16x8 a;
    if constexpr (AF32) {
      const float* A = (const float*)Ap;
      float4 f0 = make_float4(0.f, 0.f, 0.f, 0.f);
      float4 f1 = make_float4(0.f, 0.f, 0.f, 0.f);
      if (arow_ok) {
        f0 = *(const float4*)&A[(size_t)rowA * K + kk * 32 + kq * 8];
        f1 = *(const float4*)&A[(size_t)rowA * K + kk * 32 + kq * 8 + 4];
      }
      uint32x4 u;
      u[0] = (unsigned)f2bf(f0.x) | ((unsigned)f2bf(f0.y) << 16);
      u[1] = (unsigned)f2bf(f0.z) | ((unsigned)f2bf(f0.w) << 16);
      u[2] = (unsigned)f2bf(f1.x) | ((unsigned)f2bf(f1.y) << 16);
      u[3] = (unsigned)f2bf(f1.z) | ((unsigned)f2bf(f1.w) << 16);
      a = __builtin_bit_cast(bf16x8, u);
    } else {
      const ushort* A = (const ushort*)Ap;
      uint32x4 u = (uint32x4){0u, 0u, 0u, 0u};
      if (arow_ok) u = *(const uint32x4*)&A[(size_t)rowA * K + kk * 32 + kq * 8];
      a = __builtin_bit_cast(bf16x8, u);
    }
    #pragma unroll
    for (int t = 0; t < NT; ++t) {
      uint32x4 ub = *(const uint32x4*)&Bt[(size_t)(t * 16 + l15) * K + kk * 32 + kq * 8];
      bf16x8 b = __builtin_bit_cast(bf16x8, ub);
      acc[t] = __builtin_amdgcn_mfma_f32_16x16x32_bf16(a, b, acc[t], 0, 0, 0);
    }
  }

  const int rbase = blockIdx.x * 64 + wave * 16 + kq * 4;  // C/D rows

  float bcol[NT];
  #pragma unroll
  for (int t = 0; t < NT; ++t) {
    if constexpr (EPI != 1) bcol[t] = bias[t * 16 + l15];
    else bcol[t] = 0.f;
  }
  float sc[4];
  #pragma unroll
  for (int r = 0; r < 4; ++r) {
    if constexpr (EPI == 1) sc[r] = (rbase + r < n) ? dinv[rbase + r] : 0.f;
    else sc[r] = 0.f;
  }

  #pragma unroll
  for (int r = 0; r < 4; ++r) {
    int row = rbase + r;
    if (row < n) {
      #pragma unroll
      for (int t = 0; t < NT; ++t) {
        int col = t * 16 + l15;
        float v = acc[t][r];
        if constexpr (EPI == 0) {
          v += bcol[t];
          v = fmaxf(v, 0.f);
          out_bf[(size_t)row * NOUT + col] = f2bf(v);
          out_f32[(size_t)row * NOUT + col] = v;
        } else if constexpr (EPI == 1) {
          out_bf[(size_t)row * NOUT + col] = f2bf(v * sc[r]);
        } else {
          out_f32[(size_t)row * NOUT + col] = v + bcol[t];
        }
      }
    }
  }
}

// ---------------- fused SpMM (bf16 gather) + residual update ----------------
// pre[c] = bf16(dinv[c] * t[c]);  v = g*h0 + ((6-3dr^2)/dr)*pre[r] - 3dr*sum;
// h0 = v (fp32); h_bf = bf16(relu(v))
__global__ __launch_bounds__(256) void k_spmm2(const ushort* __restrict__ pre,
                                               const float* __restrict__ dinv,
                                               const int* __restrict__ rowstart,
                                               const int* __restrict__ colidx,
                                               const float* __restrict__ eps, int layer,
                                               float* __restrict__ h0,
                                               ushort* __restrict__ hbf, int n) {
  const int lane = threadIdx.x & 63;
  const int r = blockIdx.x * 4 + (threadIdx.x >> 6);
  if (r >= n) return;

  const int s0 = rowstart[r], s1 = rowstart[r + 1];
  const float dr = dinv[r];

  const size_t rowoff = (size_t)r * 128 + lane * 2;
  const unsigned ur = *(const unsigned*)&pre[rowoff];
  const float2 h0v = *(const float2*)&h0[rowoff];

  float accx = 0.f, accy = 0.f;
  for (int base = s0; base < s1; base += 64) {
    int m = s1 - base; if (m > 64) m = 64;
    int ci = 0;
    if (base + lane < s1) ci = colidx[base + lane];
    int e = 0;
    for (; e + 3 < m; e += 4) {
      int c0 = __shfl(ci, e);
      int c1 = __shfl(ci, e + 1);
      int c2 = __shfl(ci, e + 2);
      int c3 = __shfl(ci, e + 3);
      unsigned u0 = *(const unsigned*)&pre[(size_t)c0 * 128 + lane * 2];
      unsigned u1 = *(const unsigned*)&pre[(size_t)c1 * 128 + lane * 2];
      unsigned u2 = *(const unsigned*)&pre[(size_t)c2 * 128 + lane * 2];
      unsigned u3 = *(const unsigned*)&pre[(size_t)c3 * 128 + lane * 2];
      accx += __uint_as_float(u0 << 16);
      accy += __uint_as_float(u0 & 0xffff0000u);
      accx += __uint_as_float(u1 << 16);
      accy += __uint_as_float(u1 & 0xffff0000u);
      accx += __uint_as_float(u2 << 16);
      accy += __uint_as_float(u2 & 0xffff0000u);
      accx += __uint_as_float(u3 << 16);
      accy += __uint_as_float(u3 & 0xffff0000u);
    }
    for (; e < m; ++e) {
      int c = __shfl(ci, e);
      unsigned u = *(const unsigned*)&pre[(size_t)c * 128 + lane * 2];
      accx += __uint_as_float(u << 16);
      accy += __uint_as_float(u & 0xffff0000u);
    }
  }

  const float p0 = __uint_as_float(ur << 16);
  const float p1 = __uint_as_float(ur & 0xffff0000u);
  const float a = (6.0f - 3.0f * dr * dr) / dr;
  const float m3dr = -3.0f * dr;
  const float g = 1.0f + tanhf(eps[layer]);

  float v0 = g * h0v.x + a * p0 + m3dr * accx;
  float v1 = g * h0v.y + a * p1 + m3dr * accy;
  *(float2*)&h0[rowoff] = make_float2(v0, v1);
  unsigned hb = (unsigned)f2bf(fmaxf(v0, 0.f)) | ((unsigned)f2bf(fmaxf(v1, 0.f)) << 16);
  *(unsigned*)&hbf[rowoff] = hb;
}

// ---------------- launch ----------------
extern "C" void kernel_launch(void* const* d_in, const int* in_sizes, int n_in,
                              void* d_out, int out_size, void* d_ws, size_t ws_size,
                              hipStream_t stream) {
  const float* x   = (const float*)d_in[0];
  const float* W1  = (const float*)d_in[1];
  const float* b1  = (const float*)d_in[2];
  const float* Wr  = (const float*)d_in[3];
  const float* eps = (const float*)d_in[4];
  const float* W2  = (const float*)d_in[5];
  const float* b2  = (const float*)d_in[6];
  const int*   eidx= (const int*)d_in[7];

  const int IN = 256, H = 128, OUT = 64;
  const int n = in_sizes[0] / IN;   // 50000
  const int E = in_sizes[7] / 2;    // 800000
  const int L = in_sizes[4];        // 4

  size_t off = 0;
  auto carve = [&](size_t bytes) -> void* {
    void* p = (char*)d_ws + off;
    off += (bytes + 255) & ~(size_t)255;
    return p;
  };
  int*    degi     = (int*)carve((size_t)n * 4);
  int*    rowstart = (int*)carve((size_t)(n + 1) * 4);
  int*    cursor   = (int*)carve((size_t)n * 4);
  int*    bsum     = (int*)carve(64 * 4);
  int*    boff     = (int*)carve(64 * 4);
  int*    colidx   = (int*)carve((size_t)E * 4);
  float*  dinv     = (float*)carve((size_t)n * 4);
  float*  h0       = (float*)carve((size_t)n * H * 4);
  ushort* hbf      = (ushort*)carve((size_t)n * H * 2);
  ushort* pre      = (ushort*)carve((size_t)n * H * 2);
  ushort* wr_bf    = (ushort*)carve((size_t)L * H * H * 2);
  ushort* w1t      = (ushort*)carve((size_t)IN * H * 2);
  ushort* w2t      = (ushort*)carve((size_t)H * OUT * 2);
  if (off > ws_size) return;

  // ---- CSR build + weight convert ----
  hipMemsetAsync(degi, 0, (size_t)n * 4, stream);
  k_count<<<(E + 255) / 256, 256, 0, stream>>>(eidx, degi, E, n);
  int nwr = L * H * H, nw1 = IN * H, nw2 = H * OUT;
  k_cvt<<<(nwr + nw1 + nw2 + 255) / 256, 256, 0, stream>>>(Wr, W1, W2, wr_bf, w1t, w2t,
                                                           nwr, nw1, nw2);
  int nb = (n + 1023) / 1024;
  k_scan1<<<nb, 1024, 0, stream>>>(degi, rowstart, bsum, n);
  k_scan2<<<1, 64, 0, stream>>>(bsum, boff, nb);
  k_scan3<<<nb, 1024, 0, stream>>>(rowstart, boff, cursor, n, E);
  k_dinv<<<(n + 255) / 256, 256, 0, stream>>>(degi, dinv, n);
  k_fill<<<(E + 255) / 256, 256, 0, stream>>>(eidx, cursor, colidx, E, n);

  int gx = (n + 63) / 64;
  // ---- lin1 + relu -> hbf (bf16) + h0 (fp32) ----
  mfma_gemm<256, 128, true, 0><<<gx, 256, 0, stream>>>(x, w1t, b1, nullptr, hbf, h0, n);
  // ---- layers ----
  for (int l = 0; l < L; ++l) {
    mfma_gemm<128, 128, false, 1><<<gx, 256, 0, stream>>>(
        hbf, wr_bf + (size_t)l * H * H, nullptr, dinv, pre, nullptr, n);
    k_spmm2<<<(n + 3) / 4, 256, 0, stream>>>(pre, dinv, rowstart, colidx, eps, l, h0, hbf, n);
  }
  // ---- lin2 -> out (fp32) ----
  mfma_gemm<128, 64, false, 2><<<gx, 256, 0, stream>>>(hbf, w2t, b2, nullptr, nullptr,
                                                       (float*)d_out, n);
}

// Round 11
// 464.961 us; speedup vs baseline: 1.7440x; 1.0636x over previous
//
#include <hip/hip_runtime.h>
#include <math.h>

// ===========================================================================
// EnergyGCN round 10: h0 carried as bf16 (lin1 h0-write eliminated; layer-0
// h0 aliases hbf). SpMM: 2 edges per wave-load (8B/lane, shfl_xor combine),
// ushort colidx (n<65536, int fallback). dinv folded into scan3.
// GEMMs: bf16 MFMA 16x16x32 no-LDS (round 7 structure, EPI0 single write).
// ===========================================================================

typedef __bf16 bf16x8 __attribute__((ext_vector_type(8)));
typedef float f32x4 __attribute__((ext_vector_type(4)));
typedef unsigned int uint32x4 __attribute__((ext_vector_type(4)));

__device__ __forceinline__ ushort f2bf(float f) {  // RNE float->bf16
  unsigned u = __float_as_uint(f);
  return (ushort)((u + 0x7fffu + ((u >> 16) & 1u)) >> 16);
}
__device__ __forceinline__ float bflo(unsigned u) { return __uint_as_float(u << 16); }
__device__ __forceinline__ float bfhi(unsigned u) { return __uint_as_float(u & 0xffff0000u); }

// ---------------- CSR build ----------------
__global__ void k_count(const int* __restrict__ eidx, int* __restrict__ degi, int E, int n) {
  int e = blockIdx.x * blockDim.x + threadIdx.x;
  if (e < E) {
    int r = eidx[e];
    if ((unsigned)r < (unsigned)n) atomicAdd(&degi[r], 1);
  }
}

__global__ __launch_bounds__(1024) void k_scan1(const int* __restrict__ degi,
                                                int* __restrict__ rowstart,
                                                int* __restrict__ bsum, int n) {
  __shared__ int sm[1024];
  int tid = threadIdx.x;
  int i = blockIdx.x * 1024 + tid;
  int v = (i < n) ? degi[i] : 0;
  sm[tid] = v;
  __syncthreads();
  #pragma unroll
  for (int off = 1; off < 1024; off <<= 1) {
    int t = (tid >= off) ? sm[tid - off] : 0;
    __syncthreads();
    sm[tid] += t;
    __syncthreads();
  }
  if (i < n) rowstart[i] = sm[tid] - v;
  if (tid == 1023) bsum[blockIdx.x] = sm[1023];
}

__global__ void k_scan2(const int* __restrict__ bsum, int* __restrict__ boff, int nb) {
  if (threadIdx.x == 0 && blockIdx.x == 0) {
    int s = 0;
    for (int b = 0; b < nb; ++b) { boff[b] = s; s += bsum[b]; }
  }
}

// scan3 + dinv fused
__global__ __launch_bounds__(1024) void k_scan3(int* __restrict__ rowstart,
                                                const int* __restrict__ boff,
                                                int* __restrict__ cursor,
                                                const int* __restrict__ degi,
                                                float* __restrict__ dinv, int n, int E) {
  int i = blockIdx.x * 1024 + threadIdx.x;
  if (i < n) {
    int v = rowstart[i] + boff[blockIdx.x];
    rowstart[i] = v;
    cursor[i] = v;
    dinv[i] = rsqrtf((float)degi[i] + 1.0f);  // +1 = self loop
  }
  if (i == 0) rowstart[n] = E;
}

template <typename IDX>
__global__ void k_fill(const int* __restrict__ eidx, int* __restrict__ cursor,
                       IDX* __restrict__ colidx, int E, int n) {
  int e = blockIdx.x * blockDim.x + threadIdx.x;
  if (e < E) {
    int r = eidx[e];
    int c = eidx[E + e];
    if ((unsigned)r < (unsigned)n && (unsigned)c < (unsigned)n) {
      int pos = atomicAdd(&cursor[r], 1);
      colidx[pos] = (IDX)c;
    }
  }
}

// ---------------- weight convert/transpose to bf16 [j][k] ----------------
__global__ void k_cvt(const float* __restrict__ Wr, const float* __restrict__ W1,
                      const float* __restrict__ W2, ushort* __restrict__ wr_bf,
                      ushort* __restrict__ w1t, ushort* __restrict__ w2t,
                      int nwr, int nw1, int nw2) {
  int i = blockIdx.x * blockDim.x + threadIdx.x;
  if (i < nwr) {
    wr_bf[i] = f2bf(Wr[i]);
  } else if (i < nwr + nw1) {
    int m = i - nwr;             // m = k*128 + j  (W1 is [256][128])
    int k = m >> 7, j = m & 127;
    w1t[j * 256 + k] = f2bf(W1[m]);
  } else if (i < nwr + nw1 + nw2) {
    int m = i - nwr - nw1;       // m = k*64 + j   (W2 is [128][64])
    int k = m >> 6, j = m & 63;
    w2t[j * 128 + k] = f2bf(W2[m]);
  }
}

// ---------------- MFMA GEMM: C[n,NOUT] = A[n,K] @ Bt^T ----------------
// Bt bf16 [NOUT][K]. 4 waves/block, 16 rows/wave, no LDS.
// EPI 0: +bias, relu -> out_bf only (hbf)
// EPI 1: *dinv[row]  -> out_bf (pre)
// EPI 2: +bias       -> out_f32 (d_out)
template <int K, int NOUT, bool AF32, int EPI>
__global__ __launch_bounds__(256) void mfma_gemm(const void* __restrict__ Ap,
                                                 const ushort* __restrict__ Bt,
                                                 const float* __restrict__ bias,
                                                 const float* __restrict__ dinv,
                                                 ushort* __restrict__ out_bf,
                                                 float* __restrict__ out_f32,
                                                 int n) {
  constexpr int KS = K / 32;
  constexpr int NT = NOUT / 16;
  const int lane = threadIdx.x & 63;
  const int wave = threadIdx.x >> 6;
  const int l15 = lane & 15;
  const int kq = lane >> 4;
  const int rowA = blockIdx.x * 64 + wave * 16 + l15;
  const bool arow_ok = rowA < n;

  f32x4 acc[NT];
  #pragma unroll
  for (int t = 0; t < NT; ++t) acc[t] = (f32x4){0.f, 0.f, 0.f, 0.f};

  #pragma unroll
  for (int kk = 0; kk < KS; ++kk) {
    bf16x8 a;
    if constexpr (AF32) {
      const float* A = (const float*)Ap;
      float4 f0 = make_float4(0.f, 0.f, 0.f, 0.f);
      float4 f1 = make_float4(0.f, 0.f, 0.f, 0.f);
      if (arow_ok) {
        f0 = *(const float4*)&A[(size_t)rowA * K + kk * 32 + kq * 8];
        f1 = *(const float4*)&A[(size_t)rowA * K + kk * 32 + kq * 8 + 4];
      }
      uint32x4 u;
      u[0] = (unsigned)f2bf(f0.x) | ((unsigned)f2bf(f0.y) << 16);
      u[1] = (unsigned)f2bf(f0.z) | ((unsigned)f2bf(f0.w) << 16);
      u[2] = (unsigned)f2bf(f1.x) | ((unsigned)f2bf(f1.y) << 16);
      u[3] = (unsigned)f2bf(f1.z) | ((unsigned)f2bf(f1.w) << 16);
      a = __builtin_bit_cast(bf16x8, u);
    } else {
      const ushort* A = (const ushort*)Ap;
      uint32x4 u = (uint32x4){0u, 0u, 0u, 0u};
      if (arow_ok) u = *(const uint32x4*)&A[(size_t)rowA * K + kk * 32 + kq * 8];
      a = __builtin_bit_cast(bf16x8, u);
    }
    #pragma unroll
    for (int t = 0; t < NT; ++t) {
      uint32x4 ub = *(const uint32x4*)&Bt[(size_t)(t * 16 + l15) * K + kk * 32 + kq * 8];
      bf16x8 b = __builtin_bit_cast(bf16x8, ub);
      acc[t] = __builtin_amdgcn_mfma_f32_16x16x32_bf16(a, b, acc[t], 0, 0, 0);
    }
  }

  const int rbase = blockIdx.x * 64 + wave * 16 + kq * 4;  // C/D rows

  float bcol[NT];
  #pragma unroll
  for (int t = 0; t < NT; ++t) {
    if constexpr (EPI != 1) bcol[t] = bias[t * 16 + l15];
    else bcol[t] = 0.f;
  }
  float sc[4];
  #pragma unroll
  for (int r = 0; r < 4; ++r) {
    if constexpr (EPI == 1) sc[r] = (rbase + r < n) ? dinv[rbase + r] : 0.f;
    else sc[r] = 0.f;
  }

  #pragma unroll
  for (int r = 0; r < 4; ++r) {
    int row = rbase + r;
    if (row < n) {
      #pragma unroll
      for (int t = 0; t < NT; ++t) {
        int col = t * 16 + l15;
        float v = acc[t][r];
        if constexpr (EPI == 0) {
          v += bcol[t];
          v = fmaxf(v, 0.f);
          out_bf[(size_t)row * NOUT + col] = f2bf(v);
        } else if constexpr (EPI == 1) {
          out_bf[(size_t)row * NOUT + col] = f2bf(v * sc[r]);
        } else {
          out_f32[(size_t)row * NOUT + col] = v + bcol[t];
        }
      }
    }
  }
}

// ---------------- fused SpMM + residual update (all-bf16 state) ----------------
// Wave per row; lane = half*32 + c4: half selects even/odd edges, c4 owns 4 cols
// (8B). v = g*h0 + ((6-3dr^2)/dr)*pre[r] - 3dr*sum_nb(pre[c]); h0out=v; hbf=relu(v)
template <typename IDX>
__global__ __launch_bounds__(256) void k_spmm3(const ushort* __restrict__ pre,
                                               const float* __restrict__ dinv,
                                               const int* __restrict__ rowstart,
                                               const IDX* __restrict__ colidx,
                                               const float* __restrict__ eps, int layer,
                                               const ushort* __restrict__ h0in,
                                               ushort* __restrict__ h0out,
                                               ushort* __restrict__ hbf, int n) {
  const int lane = threadIdx.x & 63;
  const int r = blockIdx.x * 4 + (threadIdx.x >> 6);
  if (r >= n) return;

  const int s0 = rowstart[r], s1 = rowstart[r + 1];
  const float dr = dinv[r];
  const int half = lane >> 5;        // 0: even edges, 1: odd edges
  const int c4 = lane & 31;          // 4-col group
  const size_t rowb = (size_t)r * 128 + c4 * 4;

  const uint2 pr = *(const uint2*)&pre[rowb];
  const uint2 h0u = *(const uint2*)&h0in[rowb];

  float a0 = 0.f, a1 = 0.f, a2 = 0.f, a3 = 0.f;
  for (int base = s0; base < s1; base += 64) {
    int m = s1 - base; if (m > 64) m = 64;
    int ci = 0;
    if (base + lane < s1) ci = (int)colidx[base + lane];
    int full = m >> 1;
    int i = 0;
    for (; i + 3 < full; i += 4) {  // 4 loads in flight = 8 edges
      int cA = __shfl(ci, 2 * i + half);
      int cB = __shfl(ci, 2 * i + 2 + half);
      int cC = __shfl(ci, 2 * i + 4 + half);
      int cD = __shfl(ci, 2 * i + 6 + half);
      uint2 uA = *(const uint2*)&pre[(size_t)cA * 128 + c4 * 4];
      uint2 uB = *(const uint2*)&pre[(size_t)cB * 128 + c4 * 4];
      uint2 uC = *(const uint2*)&pre[(size_t)cC * 128 + c4 * 4];
      uint2 uD = *(const uint2*)&pre[(size_t)cD * 128 + c4 * 4];
      a0 += bflo(uA.x); a1 += bfhi(uA.x); a2 += bflo(uA.y); a3 += bfhi(uA.y);
      a0 += bflo(uB.x); a1 += bfhi(uB.x); a2 += bflo(uB.y); a3 += bfhi(uB.y);
      a0 += bflo(uC.x); a1 += bfhi(uC.x); a2 += bflo(uC.y); a3 += bfhi(uC.y);
      a0 += bflo(uD.x); a1 += bfhi(uD.x); a2 += bflo(uD.y); a3 += bfhi(uD.y);
    }
    for (; i < full; ++i) {
      int cA = __shfl(ci, 2 * i + half);
      uint2 uA = *(const uint2*)&pre[(size_t)cA * 128 + c4 * 4];
      a0 += bflo(uA.x); a1 += bfhi(uA.x); a2 += bflo(uA.y); a3 += bfhi(uA.y);
    }
    if (m & 1) {                     // odd tail: half 0 lanes take it
      int cZ = __shfl(ci, m - 1);
      if (half == 0) {
        uint2 uZ = *(const uint2*)&pre[(size_t)cZ * 128 + c4 * 4];
        a0 += bflo(uZ.x); a1 += bfhi(uZ.x); a2 += bflo(uZ.y); a3 += bfhi(uZ.y);
      }
    }
  }
  a0 += __shfl_xor(a0, 32);
  a1 += __shfl_xor(a1, 32);
  a2 += __shfl_xor(a2, 32);
  a3 += __shfl_xor(a3, 32);

  if (half == 0) {
    const float aa = (6.0f - 3.0f * dr * dr) / dr;
    const float m3 = -3.0f * dr;
    const float g = 1.0f + tanhf(eps[layer]);
    float v0 = g * bflo(h0u.x) + aa * bflo(pr.x) + m3 * a0;
    float v1 = g * bfhi(h0u.x) + aa * bfhi(pr.x) + m3 * a1;
    float v2 = g * bflo(h0u.y) + aa * bflo(pr.y) + m3 * a2;
    float v3 = g * bfhi(h0u.y) + aa * bfhi(pr.y) + m3 * a3;
    uint2 ho, hr;
    ho.x = (unsigned)f2bf(v0) | ((unsigned)f2bf(v1) << 16);
    ho.y = (unsigned)f2bf(v2) | ((unsigned)f2bf(v3) << 16);
    hr.x = (unsigned)f2bf(fmaxf(v0, 0.f)) | ((unsigned)f2bf(fmaxf(v1, 0.f)) << 16);
    hr.y = (unsigned)f2bf(fmaxf(v2, 0.f)) | ((unsigned)f2bf(fmaxf(v3, 0.f)) << 16);
    *(uint2*)&h0out[rowb] = ho;
    *(uint2*)&hbf[rowb] = hr;
  }
}

// ---------------- launch ----------------
extern "C" void kernel_launch(void* const* d_in, const int* in_sizes, int n_in,
                              void* d_out, int out_size, void* d_ws, size_t ws_size,
                              hipStream_t stream) {
  const float* x   = (const float*)d_in[0];
  const float* W1  = (const float*)d_in[1];
  const float* b1  = (const float*)d_in[2];
  const float* Wr  = (const float*)d_in[3];
  const float* eps = (const float*)d_in[4];
  const float* W2  = (const float*)d_in[5];
  const float* b2  = (const float*)d_in[6];
  const int*   eidx= (const int*)d_in[7];

  const int IN = 256, H = 128, OUT = 64;
  const int n = in_sizes[0] / IN;   // 50000
  const int E = in_sizes[7] / 2;    // 800000
  const int L = in_sizes[4];        // 4

  size_t off = 0;
  auto carve = [&](size_t bytes) -> void* {
    void* p = (char*)d_ws + off;
    off += (bytes + 255) & ~(size_t)255;
    return p;
  };
  int*    degi     = (int*)carve((size_t)n * 4);
  int*    rowstart = (int*)carve((size_t)(n + 1) * 4);
  int*    cursor   = (int*)carve((size_t)n * 4);
  int*    bsum     = (int*)carve(64 * 4);
  int*    boff     = (int*)carve(64 * 4);
  void*   colidx   = carve((size_t)E * 4);   // ushort or int
  float*  dinv     = (float*)carve((size_t)n * 4);
  ushort* h0bf     = (ushort*)carve((size_t)n * H * 2);
  ushort* hbf      = (ushort*)carve((size_t)n * H * 2);
  ushort* pre      = (ushort*)carve((size_t)n * H * 2);
  ushort* wr_bf    = (ushort*)carve((size_t)L * H * H * 2);
  ushort* w1t      = (ushort*)carve((size_t)IN * H * 2);
  ushort* w2t      = (ushort*)carve((size_t)H * OUT * 2);
  if (off > ws_size) return;

  const bool small = (n < 65536);

  // ---- CSR build + weight convert ----
  hipMemsetAsync(degi, 0, (size_t)n * 4, stream);
  k_count<<<(E + 255) / 256, 256, 0, stream>>>(eidx, degi, E, n);
  int nwr = L * H * H, nw1 = IN * H, nw2 = H * OUT;
  k_cvt<<<(nwr + nw1 + nw2 + 255) / 256, 256, 0, stream>>>(Wr, W1, W2, wr_bf, w1t, w2t,
                                                           nwr, nw1, nw2);
  int nb = (n + 1023) / 1024;
  k_scan1<<<nb, 1024, 0, stream>>>(degi, rowstart, bsum, n);
  k_scan2<<<1, 64, 0, stream>>>(bsum, boff, nb);
  k_scan3<<<nb, 1024, 0, stream>>>(rowstart, boff, cursor, degi, dinv, n, E);
  if (small)
    k_fill<ushort><<<(E + 255) / 256, 256, 0, stream>>>(eidx, cursor, (ushort*)colidx, E, n);
  else
    k_fill<int><<<(E + 255) / 256, 256, 0, stream>>>(eidx, cursor, (int*)colidx, E, n);

  int gx = (n + 63) / 64;
  // ---- lin1 + relu -> hbf (bf16 only; layer-0 h0 aliases hbf) ----
  mfma_gemm<256, 128, true, 0><<<gx, 256, 0, stream>>>(x, w1t, b1, nullptr, hbf, nullptr, n);
  // ---- layers ----
  for (int l = 0; l < L; ++l) {
    mfma_gemm<128, 128, false, 1><<<gx, 256, 0, stream>>>(
        hbf, wr_bf + (size_t)l * H * H, nullptr, dinv, pre, nullptr, n);
    const ushort* h0in = (l == 0) ? hbf : h0bf;
    if (small)
      k_spmm3<ushort><<<(n + 3) / 4, 256, 0, stream>>>(pre, dinv, rowstart,
          (const ushort*)colidx, eps, l, h0in, h0bf, hbf, n);
    else
      k_spmm3<int><<<(n + 3) / 4, 256, 0, stream>>>(pre, dinv, rowstart,
          (const int*)colidx, eps, l, h0in, h0bf, hbf, n);
  }
  // ---- lin2 -> out (fp32) ----
  mfma_gemm<128, 64, false, 2><<<gx, 256, 0, stream>>>(hbf, w2t, b2, nullptr, nullptr,
                                                       (float*)d_out, n);
}

// Round 12
// 463.278 us; speedup vs baseline: 1.7504x; 1.0036x over previous
//
#include <hip/hip_runtime.h>
#include <math.h>

// ===========================================================================
// EnergyGCN round 12: (a) GEMM col-split CW=2 -> 32 rows/block, 2x grid
// (fixes 22% occupancy / latency-bound lin1); (b) spmm4: 4 edges per
// wave-round (16 lanes x 16B per edge, 4-deep unroll = 16 loads in flight).
// Numerics identical to round 10 (bf16 h/h0/pre, fp32 out).
// ===========================================================================

typedef __bf16 bf16x8 __attribute__((ext_vector_type(8)));
typedef float f32x4 __attribute__((ext_vector_type(4)));
typedef unsigned int uint32x4 __attribute__((ext_vector_type(4)));

__device__ __forceinline__ ushort f2bf(float f) {  // RNE float->bf16
  unsigned u = __float_as_uint(f);
  return (ushort)((u + 0x7fffu + ((u >> 16) & 1u)) >> 16);
}
__device__ __forceinline__ float bflo(unsigned u) { return __uint_as_float(u << 16); }
__device__ __forceinline__ float bfhi(unsigned u) { return __uint_as_float(u & 0xffff0000u); }

// ---------------- CSR build ----------------
__global__ void k_count(const int* __restrict__ eidx, int* __restrict__ degi, int E, int n) {
  int e = blockIdx.x * blockDim.x + threadIdx.x;
  if (e < E) {
    int r = eidx[e];
    if ((unsigned)r < (unsigned)n) atomicAdd(&degi[r], 1);
  }
}

__global__ __launch_bounds__(1024) void k_scan1(const int* __restrict__ degi,
                                                int* __restrict__ rowstart,
                                                int* __restrict__ bsum, int n) {
  __shared__ int sm[1024];
  int tid = threadIdx.x;
  int i = blockIdx.x * 1024 + tid;
  int v = (i < n) ? degi[i] : 0;
  sm[tid] = v;
  __syncthreads();
  #pragma unroll
  for (int off = 1; off < 1024; off <<= 1) {
    int t = (tid >= off) ? sm[tid - off] : 0;
    __syncthreads();
    sm[tid] += t;
    __syncthreads();
  }
  if (i < n) rowstart[i] = sm[tid] - v;
  if (tid == 1023) bsum[blockIdx.x] = sm[1023];
}

__global__ void k_scan2(const int* __restrict__ bsum, int* __restrict__ boff, int nb) {
  if (threadIdx.x == 0 && blockIdx.x == 0) {
    int s = 0;
    for (int b = 0; b < nb; ++b) { boff[b] = s; s += bsum[b]; }
  }
}

// scan3 + dinv fused
__global__ __launch_bounds__(1024) void k_scan3(int* __restrict__ rowstart,
                                                const int* __restrict__ boff,
                                                int* __restrict__ cursor,
                                                const int* __restrict__ degi,
                                                float* __restrict__ dinv, int n, int E) {
  int i = blockIdx.x * 1024 + threadIdx.x;
  if (i < n) {
    int v = rowstart[i] + boff[blockIdx.x];
    rowstart[i] = v;
    cursor[i] = v;
    dinv[i] = rsqrtf((float)degi[i] + 1.0f);  // +1 = self loop
  }
  if (i == 0) rowstart[n] = E;
}

template <typename IDX>
__global__ void k_fill(const int* __restrict__ eidx, int* __restrict__ cursor,
                       IDX* __restrict__ colidx, int E, int n) {
  int e = blockIdx.x * blockDim.x + threadIdx.x;
  if (e < E) {
    int r = eidx[e];
    int c = eidx[E + e];
    if ((unsigned)r < (unsigned)n && (unsigned)c < (unsigned)n) {
      int pos = atomicAdd(&cursor[r], 1);
      colidx[pos] = (IDX)c;
    }
  }
}

// ---------------- weight convert/transpose to bf16 [j][k] ----------------
__global__ void k_cvt(const float* __restrict__ Wr, const float* __restrict__ W1,
                      const float* __restrict__ W2, ushort* __restrict__ wr_bf,
                      ushort* __restrict__ w1t, ushort* __restrict__ w2t,
                      int nwr, int nw1, int nw2) {
  int i = blockIdx.x * blockDim.x + threadIdx.x;
  if (i < nwr) {
    wr_bf[i] = f2bf(Wr[i]);
  } else if (i < nwr + nw1) {
    int m = i - nwr;             // m = k*128 + j  (W1 is [256][128])
    int k = m >> 7, j = m & 127;
    w1t[j * 256 + k] = f2bf(W1[m]);
  } else if (i < nwr + nw1 + nw2) {
    int m = i - nwr - nw1;       // m = k*64 + j   (W2 is [128][64])
    int k = m >> 6, j = m & 63;
    w2t[j * 128 + k] = f2bf(W2[m]);
  }
}

// ---------------- MFMA GEMM: C[n,NOUT] = A[n,K] @ Bt^T ----------------
// Bt bf16 [NOUT][K]. 4 waves/block = (4/CW) row-waves x CW col-waves.
// ROWS = (4/CW)*16 rows per block. EPI as before.
template <int K, int NOUT, int CW, bool AF32, int EPI>
__global__ __launch_bounds__(256) void mfma_gemm(const void* __restrict__ Ap,
                                                 const ushort* __restrict__ Bt,
                                                 const float* __restrict__ bias,
                                                 const float* __restrict__ dinv,
                                                 ushort* __restrict__ out_bf,
                                                 float* __restrict__ out_f32,
                                                 int n) {
  constexpr int KS = K / 32;
  constexpr int NT = NOUT / 16 / CW;   // col-tiles per wave
  constexpr int ROWS = (4 / CW) * 16;  // rows per block
  const int lane = threadIdx.x & 63;
  const int wave = threadIdx.x >> 6;
  const int rw = wave / CW;            // row-wave
  const int cw = wave % CW;            // col-wave
  const int l15 = lane & 15;
  const int kq = lane >> 4;
  const int col0 = cw * (NOUT / CW);
  const int rowA = blockIdx.x * ROWS + rw * 16 + l15;
  const bool arow_ok = rowA < n;

  f32x4 acc[NT];
  #pragma unroll
  for (int t = 0; t < NT; ++t) acc[t] = (f32x4){0.f, 0.f, 0.f, 0.f};

  #pragma unroll
  for (int kk = 0; kk < KS; ++kk) {
    bf16x8 a;
    if constexpr (AF32) {
      const float* A = (const float*)Ap;
      float4 f0 = make_float4(0.f, 0.f, 0.f, 0.f);
      float4 f1 = make_float4(0.f, 0.f, 0.f, 0.f);
      if (arow_ok) {
        f0 = *(const float4*)&A[(size_t)rowA * K + kk * 32 + kq * 8];
        f1 = *(const float4*)&A[(size_t)rowA * K + kk * 32 + kq * 8 + 4];
      }
      uint32x4 u;
      u[0] = (unsigned)f2bf(f0.x) | ((unsigned)f2bf(f0.y) << 16);
      u[1] = (unsigned)f2bf(f0.z) | ((unsigned)f2bf(f0.w) << 16);
      u[2] = (unsigned)f2bf(f1.x) | ((unsigned)f2bf(f1.y) << 16);
      u[3] = (unsigned)f2bf(f1.z) | ((unsigned)f2bf(f1.w) << 16);
      a = __builtin_bit_cast(bf16x8, u);
    } else {
      const ushort* A = (const ushort*)Ap;
      uint32x4 u = (uint32x4){0u, 0u, 0u, 0u};
      if (arow_ok) u = *(const uint32x4*)&A[(size_t)rowA * K + kk * 32 + kq * 8];
      a = __builtin_bit_cast(bf16x8, u);
    }
    #pragma unroll
    for (int t = 0; t < NT; ++t) {
      uint32x4 ub = *(const uint32x4*)&Bt[(size_t)(col0 + t * 16 + l15) * K + kk * 32 + kq * 8];
      bf16x8 b = __builtin_bit_cast(bf16x8, ub);
      acc[t] = __builtin_amdgcn_mfma_f32_16x16x32_bf16(a, b, acc[t], 0, 0, 0);
    }
  }

  const int rbase = blockIdx.x * ROWS + rw * 16 + kq * 4;  // C/D rows

  float bcol[NT];
  #pragma unroll
  for (int t = 0; t < NT; ++t) {
    if constexpr (EPI != 1) bcol[t] = bias[col0 + t * 16 + l15];
    else bcol[t] = 0.f;
  }
  float sc[4];
  #pragma unroll
  for (int r = 0; r < 4; ++r) {
    if constexpr (EPI == 1) sc[r] = (rbase + r < n) ? dinv[rbase + r] : 0.f;
    else sc[r] = 0.f;
  }

  #pragma unroll
  for (int r = 0; r < 4; ++r) {
    int row = rbase + r;
    if (row < n) {
      #pragma unroll
      for (int t = 0; t < NT; ++t) {
        int col = col0 + t * 16 + l15;
        float v = acc[t][r];
        if constexpr (EPI == 0) {
          v += bcol[t];
          v = fmaxf(v, 0.f);
          out_bf[(size_t)row * NOUT + col] = f2bf(v);
        } else if constexpr (EPI == 1) {
          out_bf[(size_t)row * NOUT + col] = f2bf(v * sc[r]);
        } else {
          out_f32[(size_t)row * NOUT + col] = v + bcol[t];
        }
      }
    }
  }
}

// ---------------- fused SpMM + residual (4 edges per wave-round) ----------------
// lane = quarter*16 + c8: quarter q in [0,4) owns edge 4i+q; c8 owns 8 cols (16B).
// v = g*h0 + ((6-3dr^2)/dr)*pre[r] - 3dr*sum_nb(pre[c]); h0out=v; hbf=relu(v)
template <typename IDX>
__global__ __launch_bounds__(256) void k_spmm4(const ushort* __restrict__ pre,
                                               const float* __restrict__ dinv,
                                               const int* __restrict__ rowstart,
                                               const IDX* __restrict__ colidx,
                                               const float* __restrict__ eps, int layer,
                                               const ushort* __restrict__ h0in,
                                               ushort* __restrict__ h0out,
                                               ushort* __restrict__ hbf, int n) {
  const int lane = threadIdx.x & 63;
  const int r = blockIdx.x * 4 + (threadIdx.x >> 6);
  if (r >= n) return;

  const int s0 = rowstart[r], s1 = rowstart[r + 1];
  const float dr = dinv[r];
  const int q = lane >> 4;           // quarter: edge slot
  const int c8 = lane & 15;          // 8-col group
  const size_t rowb = (size_t)r * 128 + c8 * 8;

  const uint32x4 pr = *(const uint32x4*)&pre[rowb];
  const uint32x4 h0u = *(const uint32x4*)&h0in[rowb];

  float a0 = 0.f, a1 = 0.f, a2 = 0.f, a3 = 0.f;
  float a4 = 0.f, a5 = 0.f, a6 = 0.f, a7 = 0.f;

  for (int base = s0; base < s1; base += 64) {
    int m = s1 - base; if (m > 64) m = 64;
    int ci = 0;
    if (base + lane < s1) ci = (int)colidx[base + lane];
    int full4 = m >> 2;              // groups of 4 edges
    int i = 0;
    for (; i + 3 < full4; i += 4) {  // 16 edges, 4 loads in flight/lane
      int cA = __shfl(ci, 4 * i + q);
      int cB = __shfl(ci, 4 * i + 4 + q);
      int cC = __shfl(ci, 4 * i + 8 + q);
      int cD = __shfl(ci, 4 * i + 12 + q);
      uint32x4 uA = *(const uint32x4*)&pre[(size_t)cA * 128 + c8 * 8];
      uint32x4 uB = *(const uint32x4*)&pre[(size_t)cB * 128 + c8 * 8];
      uint32x4 uC = *(const uint32x4*)&pre[(size_t)cC * 128 + c8 * 8];
      uint32x4 uD = *(const uint32x4*)&pre[(size_t)cD * 128 + c8 * 8];
      a0 += bflo(uA[0]); a1 += bfhi(uA[0]); a2 += bflo(uA[1]); a3 += bfhi(uA[1]);
      a4 += bflo(uA[2]); a5 += bfhi(uA[2]); a6 += bflo(uA[3]); a7 += bfhi(uA[3]);
      a0 += bflo(uB[0]); a1 += bfhi(uB[0]); a2 += bflo(uB[1]); a3 += bfhi(uB[1]);
      a4 += bflo(uB[2]); a5 += bfhi(uB[2]); a6 += bflo(uB[3]); a7 += bfhi(uB[3]);
      a0 += bflo(uC[0]); a1 += bfhi(uC[0]); a2 += bflo(uC[1]); a3 += bfhi(uC[1]);
      a4 += bflo(uC[2]); a5 += bfhi(uC[2]); a6 += bflo(uC[3]); a7 += bfhi(uC[3]);
      a0 += bflo(uD[0]); a1 += bfhi(uD[0]); a2 += bflo(uD[1]); a3 += bfhi(uD[1]);
      a4 += bflo(uD[2]); a5 += bfhi(uD[2]); a6 += bflo(uD[3]); a7 += bfhi(uD[3]);
    }
    for (; i < full4; ++i) {
      int cA = __shfl(ci, 4 * i + q);
      uint32x4 uA = *(const uint32x4*)&pre[(size_t)cA * 128 + c8 * 8];
      a0 += bflo(uA[0]); a1 += bfhi(uA[0]); a2 += bflo(uA[1]); a3 += bfhi(uA[1]);
      a4 += bflo(uA[2]); a5 += bfhi(uA[2]); a6 += bflo(uA[3]); a7 += bfhi(uA[3]);
    }
    int rem = m & 3;                 // tail: quarters q < rem take one edge
    if (rem) {
      int cZ = __shfl(ci, full4 * 4 + (q < rem ? q : 0));
      if (q < rem) {
        uint32x4 uZ = *(const uint32x4*)&pre[(size_t)cZ * 128 + c8 * 8];
        a0 += bflo(uZ[0]); a1 += bfhi(uZ[0]); a2 += bflo(uZ[1]); a3 += bfhi(uZ[1]);
        a4 += bflo(uZ[2]); a5 += bfhi(uZ[2]); a6 += bflo(uZ[3]); a7 += bfhi(uZ[3]);
      }
    }
  }
  // quarter-combine: q0<-q1 (xor16), then (q0q1)<-(q2q3) (xor32)
  a0 += __shfl_xor(a0, 16); a1 += __shfl_xor(a1, 16);
  a2 += __shfl_xor(a2, 16); a3 += __shfl_xor(a3, 16);
  a4 += __shfl_xor(a4, 16); a5 += __shfl_xor(a5, 16);
  a6 += __shfl_xor(a6, 16); a7 += __shfl_xor(a7, 16);
  a0 += __shfl_xor(a0, 32); a1 += __shfl_xor(a1, 32);
  a2 += __shfl_xor(a2, 32); a3 += __shfl_xor(a3, 32);
  a4 += __shfl_xor(a4, 32); a5 += __shfl_xor(a5, 32);
  a6 += __shfl_xor(a6, 32); a7 += __shfl_xor(a7, 32);

  if (q == 0) {
    const float aa = (6.0f - 3.0f * dr * dr) / dr;
    const float m3 = -3.0f * dr;
    const float g = 1.0f + tanhf(eps[layer]);
    float v0 = g * bflo(h0u[0]) + aa * bflo(pr[0]) + m3 * a0;
    float v1 = g * bfhi(h0u[0]) + aa * bfhi(pr[0]) + m3 * a1;
    float v2 = g * bflo(h0u[1]) + aa * bflo(pr[1]) + m3 * a2;
    float v3 = g * bfhi(h0u[1]) + aa * bfhi(pr[1]) + m3 * a3;
    float v4 = g * bflo(h0u[2]) + aa * bflo(pr[2]) + m3 * a4;
    float v5 = g * bfhi(h0u[2]) + aa * bfhi(pr[2]) + m3 * a5;
    float v6 = g * bflo(h0u[3]) + aa * bflo(pr[3]) + m3 * a6;
    float v7 = g * bfhi(h0u[3]) + aa * bfhi(pr[3]) + m3 * a7;
    uint32x4 ho, hr;
    ho[0] = (unsigned)f2bf(v0) | ((unsigned)f2bf(v1) << 16);
    ho[1] = (unsigned)f2bf(v2) | ((unsigned)f2bf(v3) << 16);
    ho[2] = (unsigned)f2bf(v4) | ((unsigned)f2bf(v5) << 16);
    ho[3] = (unsigned)f2bf(v6) | ((unsigned)f2bf(v7) << 16);
    hr[0] = (unsigned)f2bf(fmaxf(v0, 0.f)) | ((unsigned)f2bf(fmaxf(v1, 0.f)) << 16);
    hr[1] = (unsigned)f2bf(fmaxf(v2, 0.f)) | ((unsigned)f2bf(fmaxf(v3, 0.f)) << 16);
    hr[2] = (unsigned)f2bf(fmaxf(v4, 0.f)) | ((unsigned)f2bf(fmaxf(v5, 0.f)) << 16);
    hr[3] = (unsigned)f2bf(fmaxf(v6, 0.f)) | ((unsigned)f2bf(fmaxf(v7, 0.f)) << 16);
    *(uint32x4*)&h0out[rowb] = ho;
    *(uint32x4*)&hbf[rowb] = hr;
  }
}

// ---------------- launch ----------------
extern "C" void kernel_launch(void* const* d_in, const int* in_sizes, int n_in,
                              void* d_out, int out_size, void* d_ws, size_t ws_size,
                              hipStream_t stream) {
  const float* x   = (const float*)d_in[0];
  const float* W1  = (const float*)d_in[1];
  const float* b1  = (const float*)d_in[2];
  const float* Wr  = (const float*)d_in[3];
  const float* eps = (const float*)d_in[4];
  const float* W2  = (const float*)d_in[5];
  const float* b2  = (const float*)d_in[6];
  const int*   eidx= (const int*)d_in[7];

  const int IN = 256, H = 128, OUT = 64;
  const int n = in_sizes[0] / IN;   // 50000
  const int E = in_sizes[7] / 2;    // 800000
  const int L = in_sizes[4];        // 4

  size_t off = 0;
  auto carve = [&](size_t bytes) -> void* {
    void* p = (char*)d_ws + off;
    off += (bytes + 255) & ~(size_t)255;
    return p;
  };
  int*    degi     = (int*)carve((size_t)n * 4);
  int*    rowstart = (int*)carve((size_t)(n + 1) * 4);
  int*    cursor   = (int*)carve((size_t)n * 4);
  int*    bsum     = (int*)carve(64 * 4);
  int*    boff     = (int*)carve(64 * 4);
  void*   colidx   = carve((size_t)E * 4);   // ushort or int
  float*  dinv     = (float*)carve((size_t)n * 4);
  ushort* h0bf     = (ushort*)carve((size_t)n * H * 2);
  ushort* hbf      = (ushort*)carve((size_t)n * H * 2);
  ushort* pre      = (ushort*)carve((size_t)n * H * 2);
  ushort* wr_bf    = (ushort*)carve((size_t)L * H * H * 2);
  ushort* w1t      = (ushort*)carve((size_t)IN * H * 2);
  ushort* w2t      = (ushort*)carve((size_t)H * OUT * 2);
  if (off > ws_size) return;

  const bool small = (n < 65536);

  // ---- CSR build + weight convert ----
  hipMemsetAsync(degi, 0, (size_t)n * 4, stream);
  k_count<<<(E + 255) / 256, 256, 0, stream>>>(eidx, degi, E, n);
  int nwr = L * H * H, nw1 = IN * H, nw2 = H * OUT;
  k_cvt<<<(nwr + nw1 + nw2 + 255) / 256, 256, 0, stream>>>(Wr, W1, W2, wr_bf, w1t, w2t,
                                                           nwr, nw1, nw2);
  int nb = (n + 1023) / 1024;
  k_scan1<<<nb, 1024, 0, stream>>>(degi, rowstart, bsum, n);
  k_scan2<<<1, 64, 0, stream>>>(bsum, boff, nb);
  k_scan3<<<nb, 1024, 0, stream>>>(rowstart, boff, cursor, degi, dinv, n, E);
  if (small)
    k_fill<ushort><<<(E + 255) / 256, 256, 0, stream>>>(eidx, cursor, (ushort*)colidx, E, n);
  else
    k_fill<int><<<(E + 255) / 256, 256, 0, stream>>>(eidx, cursor, (int*)colidx, E, n);

  int gx32 = (n + 31) / 32;
  // ---- lin1 + relu -> hbf (bf16; layer-0 h0 aliases hbf) ----
  mfma_gemm<256, 128, 2, true, 0><<<gx32, 256, 0, stream>>>(x, w1t, b1, nullptr, hbf,
                                                            nullptr, n);
  // ---- layers ----
  for (int l = 0; l < L; ++l) {
    mfma_gemm<128, 128, 2, false, 1><<<gx32, 256, 0, stream>>>(
        hbf, wr_bf + (size_t)l * H * H, nullptr, dinv, pre, nullptr, n);
    const ushort* h0in = (l == 0) ? hbf : h0bf;
    if (small)
      k_spmm4<ushort><<<(n + 3) / 4, 256, 0, stream>>>(pre, dinv, rowstart,
          (const ushort*)colidx, eps, l, h0in, h0bf, hbf, n);
    else
      k_spmm4<int><<<(n + 3) / 4, 256, 0, stream>>>(pre, dinv, rowstart,
          (const int*)colidx, eps, l, h0in, h0bf, hbf, n);
  }
  // ---- lin2 -> out (fp32) ----
  mfma_gemm<128, 64, 2, false, 2><<<gx32, 256, 0, stream>>>(hbf, w2t, b2, nullptr, nullptr,
                                                            (float*)d_out, n);
}